// Round 9
// baseline (187.610 us; speedup 1.0000x reference)
//
#include <hip/hip_runtime.h>
#include <stdint.h>

// Problem constants: B=2048, C=200, F=32, H=256. All tensors fp32 in/out.
// M = B*C = 409600 rows of 32 features, contiguous in x.
#define M_ROWS 409600
#define B_CNT  2048
#define C_CNT  200
#define N_TILES (M_ROWS / 64)    // 6400 tiles of 64 rows
#define GRID_MLP 512             // persistent blocks: 2 per CU

typedef __attribute__((ext_vector_type(8))) short bf16x8;   // 8 bf16 = 4 VGPRs
typedef __attribute__((ext_vector_type(4))) float f32x4;

// round-to-nearest-even f32 -> bf16 bits (scalar path, prep kernel)
__device__ __forceinline__ ushort f2bf(float f) {
    uint32_t u = __float_as_uint(f);
    u += 0x7fffu + ((u >> 16) & 1u);
    return (ushort)(u >> 16);
}

// packed RNE f32x2 -> bf16x2 (single HW instruction)
__device__ __forceinline__ uint32_t cvtpk_bf16(float lo, float hi) {
    uint32_t r;
    asm("v_cvt_pk_bf16_f32 %0, %1, %2" : "=v"(r) : "v"(lo), "v"(hi));
    return r;
}

__device__ __forceinline__ f32x4 mfma16(bf16x8 a, bf16x8 b, f32x4 c) {
    return __builtin_amdgcn_mfma_f32_16x16x32_bf16(a, b, c, 0, 0, 0);
}

__device__ __forceinline__ bf16x8 pack8(float4 a, float4 b) {
    bf16x8 r;
    r[0] = (short)f2bf(a.x); r[1] = (short)f2bf(a.y);
    r[2] = (short)f2bf(a.z); r[3] = (short)f2bf(a.w);
    r[4] = (short)f2bf(b.x); r[5] = (short)f2bf(b.y);
    r[6] = (short)f2bf(b.z); r[7] = (short)f2bf(b.w);
    return r;
}

// ---------------------------------------------------------------------------
// Prep kernel (unchanged, measured-good):
//   blocks [0,2048):   one coalesced pass over the x row: bf16 copy (xb16),
//                      sinflow/iinflow, fused epilogue operand
//                      epi[gm] = {S, P, Q, 0}:
//                        P = S + sinflow - outflow*S,  Q = I + iinflow - outflow*I
//   blocks [2048,2304): W2^T -> bf16
//   blocks [2304,2336): W1^T -> bf16
// ---------------------------------------------------------------------------
__global__ __launch_bounds__(256) void prep_kernel(
    const float* __restrict__ x, const float* __restrict__ T,
    const float* __restrict__ W1, const float* __restrict__ W2,
    ushort* __restrict__ xb16, float4* __restrict__ epi,
    ushort* __restrict__ W1t, ushort* __restrict__ W2t, int do_xb) {
    int blk = blockIdx.x, t = threadIdx.x;
    if (blk < B_CNT) {
        __shared__ float Sr[C_CNT], Ir[C_CNT];
        const float4* xr = (const float4*)(x + (size_t)blk * 6400);  // 1600 f4
        ushort4* xw = (ushort4*)(xb16 + (size_t)blk * 6400);
#pragma unroll
        for (int i = 0; i < 7; ++i) {
            int i4 = i * 256 + t;
            if (i4 < 1600) {
                float4 v = xr[i4];
                if (do_xb) {
                    ushort4 u;
                    u.x = f2bf(v.x); u.y = f2bf(v.y);
                    u.z = f2bf(v.z); u.w = f2bf(v.w);
                    xw[i4] = u;
                }
                if ((i4 & 7) == 0) {           // element i4*4 is feature 0 of c
                    int c = i4 >> 3;
                    Sr[c] = v.x; Ir[c] = v.y;
                }
            }
        }
        __syncthreads();
        if (t < C_CNT) {
            float as = 0.f, ai = 0.f;
            for (int cp = 0; cp < C_CNT; ++cp) {
                float tv = T[cp * C_CNT + t];        // coalesced over t, L2-hot
                as = fmaf(Sr[cp], tv, as);
                ai = fmaf(Ir[cp], tv, ai);
            }
            float S = Sr[t], I = Ir[t];
            float of = 1.0f - T[t * C_CNT + t];
            float4 e;
            e.x = S;
            e.y = S + as - of * S;   // P
            e.z = I + ai - of * I;   // Q
            e.w = 0.f;
            epi[(size_t)blk * C_CNT + t] = e;
        }
    } else if (blk < B_CNT + 256) {
        int n = blk - B_CNT;                          // one n2 row per block
        W2t[n * 256 + t] = f2bf(W2[t * 256 + n]);     // write coalesced
    } else {
        int idx = (blk - B_CNT - 256) * 256 + t;      // 0..8191
        int n = idx >> 5, k = idx & 31;
        W1t[idx] = f2bf(W1[k * 256 + n]);
    }
}

// ---------------------------------------------------------------------------
// Persistent fused MLP kernel — r7 structure (4 waves, 2 blocks/CU, one
// barrier/tile, bx register prefetch after GEMM2) with two fixes:
//  (1) h1s rows are 512 B (power of 2) with a 16B-granular XOR swizzle
//      col ^= (m&7)<<4 applied on BOTH the pack write and the GEMM2
//      ds_read_b128 -> bank-conflict-free (RS-pad could not fix the L/L+8
//      collision since any 16B-aligned stride is = 4k dwords mod 32).
//  (2) epilogue + epi prefetch + store distributed across all 4 waves
//      (lanes q==0 of wave w own rows 16w..16w+15) -> no wave-0 barrier
//      straggler.
// Per iteration t:
//   [chunk c=0,1: aw(2) load | 8 MFMA GEMM1 | pack 32 cols -> h1s[buf] swz]
//   BARRIER | epilogue(t-1) all waves | GEMM2(t) regs x LDS (swz reads)
//   | bx reload(t+1) (after the register peak) | epi prefetch(t) | GEMM3(t)
// ---------------------------------------------------------------------------
template <bool XB>
__global__ __launch_bounds__(256, 2) void mlp_kernel(
    const float* __restrict__ x,
    const ushort* __restrict__ xb16,
    const float* __restrict__ b1,
    const float* __restrict__ b2,
    const float* __restrict__ W3,
    const float* __restrict__ b3,
    const ushort* __restrict__ W1t,   // [256][32]  bf16, n1-major
    const ushort* __restrict__ W2t,   // [256][256] bf16, n2-major
    const float4* __restrict__ epi,   // {S, P, Q, 0} per row
    float* __restrict__ out) {
    __shared__ ushort h1s[2][64 * 256];      // 2 x 32768 B, 512B rows, XOR-swz
    __shared__ float b1f[256], b2f[256], w3f[256];
    __shared__ float lamb2[2][4][64];        // parity double buffer
    // LDS total: 65536 + 3072 + 2048 = 70656 B  (2 blocks/CU)

    const int tid  = threadIdx.x;
    const int w    = tid >> 6;
    const int lane = tid & 63;
    const int L    = lane & 15;
    const int q    = lane >> 4;

    b1f[tid] = b1[tid];
    b2f[tid] = b2[tid];
    w3f[tid] = W3[tid];
    const float b3v = b3[0];

    // ---- register-resident W2t slice (loaded once, reused every tile) ----
    bf16x8 a2r[4][8];                 // [i2][kc]
#pragma unroll
    for (int i2 = 0; i2 < 4; ++i2)
#pragma unroll
        for (int kc = 0; kc < 8; ++kc)
            a2r[i2][kc] =
                *(const bf16x8*)(W2t + (64 * w + i2 * 16 + L) * 256 + kc * 32 + q * 8);

    // W1t fragment byte-offset (32-bit, SGPR base); laundered per iteration
    uint32_t w1off = (uint32_t)(((64 * w + L) * 32 + q * 8) * sizeof(ushort));

    // ---- prologue: preload bx for the first tile ----
    int tile = blockIdx.x;
    bf16x8 bx[4];
#pragma unroll
    for (int i = 0; i < 4; ++i) {
        if (XB) {
            bx[i] = *(const bf16x8*)(xb16 + (size_t)(tile * 64 + i * 16 + L) * 32 + q * 8);
        } else {
            const float4* xr =
                (const float4*)(x + (size_t)(tile * 64 + i * 16 + L) * 32 + q * 8);
            bx[i] = pack8(xr[0], xr[1]);
        }
    }

    // epilogue operands: lanes with q==0 of wave w own rows 16w..16w+15
    const int erow = w * 16 + L;          // row within tile (q==0 lanes only)
    float eS = 0.f, eP = 0.f, eQ = 0.f;
    int ptile = -1;      // tile whose epilogue is pending
    int buf = 0, wp = 0;

    __syncthreads();     // b1f/b2f/w3f visible

    for (; tile < N_TILES; tile += GRID_MLP) {
        // ---- GEMM1+pack in TWO chunks (acc1 live range = 32 regs) ----
        asm volatile("" : "+v"(w1off));
        const char* w1p = (const char*)W1t + w1off;
#pragma unroll
        for (int c = 0; c < 2; ++c) {
            bf16x8 aw[2];
#pragma unroll
            for (int i = 0; i < 2; ++i)
                aw[i] = *(const bf16x8*)(w1p + (size_t)(c * 2 + i) * 1024);

            f32x4 acc1[2][4];
#pragma unroll
            for (int i1 = 0; i1 < 2; ++i1)
#pragma unroll
                for (int im = 0; im < 4; ++im)
                    acc1[i1][im] = mfma16(aw[i1], bx[im], (f32x4){0.f, 0.f, 0.f, 0.f});

            // pack 32 n1-columns (bias+relu fp32, cvt_pk bf16) -> h1s[buf] swz
            // Safe pre-barrier: buf == buf(t-2); all waves passed barrier(t-1),
            // whose program order puts GEMM2(t-2) (last reader of buf) first.
#pragma unroll
            for (int i1 = 0; i1 < 2; ++i1) {
                int n1b = 64 * w + (c * 2 + i1) * 16 + q * 4;
                const float4 bv = *reinterpret_cast<const float4*>(&b1f[n1b]);
#pragma unroll
                for (int im = 0; im < 4; ++im) {
                    int m = im * 16 + L;
                    float v0 = fmaxf(acc1[i1][im][0] + bv.x, 0.f);
                    float v1 = fmaxf(acc1[i1][im][1] + bv.y, 0.f);
                    float v2 = fmaxf(acc1[i1][im][2] + bv.z, 0.f);
                    float v3 = fmaxf(acc1[i1][im][3] + bv.w, 0.f);
                    uint2 pk;
                    pk.x = cvtpk_bf16(v0, v1);
                    pk.y = cvtpk_bf16(v2, v3);
                    uint32_t col = (uint32_t)(n1b * 2) ^ ((uint32_t)(m & 7) << 4);
                    *reinterpret_cast<uint2*>(
                        (char*)&h1s[buf][0] + m * 512 + col) = pk;
                }
            }
        }

        __syncthreads();   // THE barrier: h1s[buf] ready; lamb2[wp^1] visible

        // ---- pipelined epilogue for tile t-1 — DISTRIBUTED across waves ----
        if (ptile >= 0 && q == 0) {
            int gm = ptile * 64 + erow;
            float lam = lamb2[wp ^ 1][0][erow] + lamb2[wp ^ 1][1][erow] +
                        lamb2[wp ^ 1][2][erow] + lamb2[wp ^ 1][3][erow] + b3v;
            float2 o;
            o.x = eP - lam * eS;
            o.y = eQ + lam * eS;
            ((float2*)out)[gm] = o;   // 128B contiguous per wave
        }

        // ---- GEMM2 (K=256, 8 k-chunks): A from registers, B from LDS ----
        f32x4 acc2[4][4];
#pragma unroll
        for (int i2 = 0; i2 < 4; ++i2)
#pragma unroll
            for (int im = 0; im < 4; ++im) acc2[i2][im] = (f32x4){0.f, 0.f, 0.f, 0.f};

#pragma unroll
        for (int kc = 0; kc < 8; ++kc) {
            bf16x8 bh[4];
#pragma unroll
            for (int im = 0; im < 4; ++im) {
                int m = im * 16 + L;
                uint32_t col = (uint32_t)(kc * 64 + q * 16) ^ ((uint32_t)(m & 7) << 4);
                bh[im] = *(const bf16x8*)((const char*)&h1s[buf][0] + m * 512 + col);
            }
#pragma unroll
            for (int i2 = 0; i2 < 4; ++i2)
#pragma unroll
                for (int im = 0; im < 4; ++im)
                    acc2[i2][im] = mfma16(a2r[i2][kc], bh[im], acc2[i2][im]);
        }

        // ---- bx reload for next tile: AFTER the GEMM2 register peak ----
        {
            int tn = tile + GRID_MLP;
            if (tn >= N_TILES) tn = tile;   // harmless dummy reload on last iter
            const size_t mn0 = (size_t)tn * 64;
#pragma unroll
            for (int i = 0; i < 4; ++i) {
                if (XB) {
                    bx[i] = *(const bf16x8*)(xb16 + (mn0 + i * 16 + L) * 32 + q * 8);
                } else {
                    const float4* xr =
                        (const float4*)(x + (mn0 + i * 16 + L) * 32 + q * 8);
                    bx[i] = pack8(xr[0], xr[1]);
                }
            }
        }

        // ---- prefetch epilogue operands for THIS tile — distributed ----
        if (q == 0) {
            float4 e = epi[(size_t)tile * 64 + erow];
            eS = e.x; eP = e.y; eQ = e.z;
        }

        // ---- GEMM3: lamb[m] = sum_n2 relu(h2 + b2) * W3 (fp32, exact) ----
        float part[4] = {0.f, 0.f, 0.f, 0.f};
#pragma unroll
        for (int i2 = 0; i2 < 4; ++i2) {
            int n2b = 64 * w + i2 * 16 + q * 4;
            const float4 b2v = *reinterpret_cast<const float4*>(&b2f[n2b]);
            const float4 w3v = *reinterpret_cast<const float4*>(&w3f[n2b]);
#pragma unroll
            for (int im = 0; im < 4; ++im) {
                float h0 = fmaxf(acc2[i2][im][0] + b2v.x, 0.f);
                float h1 = fmaxf(acc2[i2][im][1] + b2v.y, 0.f);
                float h2 = fmaxf(acc2[i2][im][2] + b2v.z, 0.f);
                float h3 = fmaxf(acc2[i2][im][3] + b2v.w, 0.f);
                part[im] = fmaf(h0, w3v.x, part[im]);
                part[im] = fmaf(h1, w3v.y, part[im]);
                part[im] = fmaf(h2, w3v.z, part[im]);
                part[im] = fmaf(h3, w3v.w, part[im]);
            }
        }

#pragma unroll
        for (int im = 0; im < 4; ++im) {
            float pp = part[im];
            pp += __shfl_xor(pp, 16);
            pp += __shfl_xor(pp, 32);
            if (q == 0) lamb2[wp][w][im * 16 + L] = pp;
        }
        // lamb2[wp] is consumed only after the NEXT barrier.

        ptile = tile;
        buf ^= 1;
        wp ^= 1;
    }

    // ---- drain: epilogue for the final tile ----
    __syncthreads();
    if (ptile >= 0 && q == 0) {
        int gm = ptile * 64 + erow;
        float lam = lamb2[wp ^ 1][0][erow] + lamb2[wp ^ 1][1][erow] +
                    lamb2[wp ^ 1][2][erow] + lamb2[wp ^ 1][3][erow] + b3v;
        float2 o;
        o.x = eP - lam * eS;
        o.y = eQ + lam * eS;
        ((float2*)out)[gm] = o;
    }
}

// ---------------------------------------------------------------------------
extern "C" void kernel_launch(void* const* d_in, const int* in_sizes, int n_in,
                              void* d_out, int out_size, void* d_ws, size_t ws_size,
                              hipStream_t stream) {
    const float* x  = (const float*)d_in[0];
    const float* T  = (const float*)d_in[1];
    const float* W1 = (const float*)d_in[2];
    const float* b1 = (const float*)d_in[3];
    const float* W2 = (const float*)d_in[4];
    const float* b2 = (const float*)d_in[5];
    const float* W3 = (const float*)d_in[6];
    const float* b3 = (const float*)d_in[7];

    // ws layout: [xb16 (opt, 26.2 MB)] epi (6.55 MB) W1t (16KB) W2t (128KB)
    const size_t xb_bytes = (size_t)M_ROWS * 32 * 2;
    const size_t epi_b    = (size_t)M_ROWS * 16;
    const size_t small    = epi_b + 8192 * 2 + 65536 * 2;
    const int    do_xb    = (ws_size >= xb_bytes + small) ? 1 : 0;

    char* ws = (char*)d_ws;
    ushort* xb16 = (ushort*)ws;
    char* base = ws + (do_xb ? xb_bytes : 0);
    float4* epi  = (float4*)(base);
    ushort* W1t  = (ushort*)(base + epi_b);
    ushort* W2t  = (ushort*)(base + epi_b + 8192 * 2);

    hipLaunchKernelGGL(prep_kernel, dim3(B_CNT + 256 + 32), dim3(256), 0, stream,
                       x, T, W1, W2, xb16, epi, W1t, W2t, do_xb);
    if (do_xb) {
        hipLaunchKernelGGL((mlp_kernel<true>), dim3(GRID_MLP), dim3(256), 0, stream,
                           x, xb16, b1, b2, W3, b3, W1t, W2t, epi, (float*)d_out);
    } else {
        hipLaunchKernelGGL((mlp_kernel<false>), dim3(GRID_MLP), dim3(256), 0, stream,
                           x, xb16, b1, b2, W3, b3, W1t, W2t, epi, (float*)d_out);
    }
}

// Round 10
// 184.349 us; speedup vs baseline: 1.0177x; 1.0177x over previous
//
#include <hip/hip_runtime.h>
#include <stdint.h>

// Problem constants: B=2048, C=200, F=32, H=256. All tensors fp32 in/out.
// M = B*C = 409600 rows of 32 features, contiguous in x.
#define M_ROWS 409600
#define B_CNT  2048
#define C_CNT  200
#define N_TILES (M_ROWS / 64)    // 6400 tiles of 64 rows
#define GRID_MLP 512             // persistent blocks: 2 per CU

typedef __attribute__((ext_vector_type(8))) short bf16x8;   // 8 bf16 = 4 VGPRs
typedef __attribute__((ext_vector_type(4))) float f32x4;

constexpr int RS = 264;  // h1 row stride (ushorts): rows 16B-aligned.
// NOTE: SQ_LDS_BANK_CONFLICT ~4.92M/dispatch is the INHERENT serialization of
// wave64 ds_read_b128 (1KB/wave over 128B/clk banks) — measured invariant
// across RS-pad and XOR-swizzle layouts (r7 vs r9). Not a fixable conflict.

// round-to-nearest-even f32 -> bf16 bits (scalar path, prep kernel)
__device__ __forceinline__ ushort f2bf(float f) {
    uint32_t u = __float_as_uint(f);
    u += 0x7fffu + ((u >> 16) & 1u);
    return (ushort)(u >> 16);
}

// packed RNE f32x2 -> bf16x2 (single HW instruction)
__device__ __forceinline__ uint32_t cvtpk_bf16(float lo, float hi) {
    uint32_t r;
    asm("v_cvt_pk_bf16_f32 %0, %1, %2" : "=v"(r) : "v"(lo), "v"(hi));
    return r;
}

__device__ __forceinline__ f32x4 mfma16(bf16x8 a, bf16x8 b, f32x4 c) {
    return __builtin_amdgcn_mfma_f32_16x16x32_bf16(a, b, c, 0, 0, 0);
}

__device__ __forceinline__ bf16x8 pack8(float4 a, float4 b) {
    bf16x8 r;
    r[0] = (short)f2bf(a.x); r[1] = (short)f2bf(a.y);
    r[2] = (short)f2bf(a.z); r[3] = (short)f2bf(a.w);
    r[4] = (short)f2bf(b.x); r[5] = (short)f2bf(b.y);
    r[6] = (short)f2bf(b.z); r[7] = (short)f2bf(b.w);
    return r;
}

// ---------------------------------------------------------------------------
// Prep kernel (unchanged, measured-good):
//   blocks [0,2048):   one coalesced pass over the x row: bf16 copy (xb16),
//                      sinflow/iinflow, fused epilogue operand
//                      epi[gm] = {S, P, Q, 0}:
//                        P = S + sinflow - outflow*S,  Q = I + iinflow - outflow*I
//   blocks [2048,2304): W2^T -> bf16
//   blocks [2304,2336): W1^T -> bf16
// ---------------------------------------------------------------------------
__global__ __launch_bounds__(256) void prep_kernel(
    const float* __restrict__ x, const float* __restrict__ T,
    const float* __restrict__ W1, const float* __restrict__ W2,
    ushort* __restrict__ xb16, float4* __restrict__ epi,
    ushort* __restrict__ W1t, ushort* __restrict__ W2t, int do_xb) {
    int blk = blockIdx.x, t = threadIdx.x;
    if (blk < B_CNT) {
        __shared__ float Sr[C_CNT], Ir[C_CNT];
        const float4* xr = (const float4*)(x + (size_t)blk * 6400);  // 1600 f4
        ushort4* xw = (ushort4*)(xb16 + (size_t)blk * 6400);
#pragma unroll
        for (int i = 0; i < 7; ++i) {
            int i4 = i * 256 + t;
            if (i4 < 1600) {
                float4 v = xr[i4];
                if (do_xb) {
                    ushort4 u;
                    u.x = f2bf(v.x); u.y = f2bf(v.y);
                    u.z = f2bf(v.z); u.w = f2bf(v.w);
                    xw[i4] = u;
                }
                if ((i4 & 7) == 0) {           // element i4*4 is feature 0 of c
                    int c = i4 >> 3;
                    Sr[c] = v.x; Ir[c] = v.y;
                }
            }
        }
        __syncthreads();
        if (t < C_CNT) {
            float as = 0.f, ai = 0.f;
            for (int cp = 0; cp < C_CNT; ++cp) {
                float tv = T[cp * C_CNT + t];        // coalesced over t, L2-hot
                as = fmaf(Sr[cp], tv, as);
                ai = fmaf(Ir[cp], tv, ai);
            }
            float S = Sr[t], I = Ir[t];
            float of = 1.0f - T[t * C_CNT + t];
            float4 e;
            e.x = S;
            e.y = S + as - of * S;   // P
            e.z = I + ai - of * I;   // Q
            e.w = 0.f;
            epi[(size_t)blk * C_CNT + t] = e;
        }
    } else if (blk < B_CNT + 256) {
        int n = blk - B_CNT;                          // one n2 row per block
        W2t[n * 256 + t] = f2bf(W2[t * 256 + n]);     // write coalesced
    } else {
        int idx = (blk - B_CNT - 256) * 256 + t;      // 0..8191
        int n = idx >> 5, k = idx & 31;
        W1t[idx] = f2bf(W1[k * 256 + n]);
    }
}

// ---------------------------------------------------------------------------
// Per-tile building blocks (force-inlined; r7-identical internals).
// ---------------------------------------------------------------------------
template <bool XB>
__device__ __forceinline__ void load_bx(bf16x8 (&bx)[4],
                                        const ushort* __restrict__ xb16,
                                        const float* __restrict__ x,
                                        int t, int L, int q) {
#pragma unroll
    for (int i = 0; i < 4; ++i) {
        if (XB) {
            bx[i] = *(const bf16x8*)(xb16 + (size_t)(t * 64 + i * 16 + L) * 32 + q * 8);
        } else {
            const float4* xr =
                (const float4*)(x + (size_t)(t * 64 + i * 16 + L) * 32 + q * 8);
            bx[i] = pack8(xr[0], xr[1]);
        }
    }
}

// GEMM1 (K=32, two i1-chunks so acc1 live range = 32 regs) + bias/relu/cvt_pk
// pack into h1buf.
__device__ __forceinline__ void tile_front(
    uint32_t& w1off, const ushort* __restrict__ W1t, const bf16x8 (&bx)[4],
    ushort* __restrict__ h1buf, const float* __restrict__ b1f,
    int w, int L, int q) {
    asm volatile("" : "+v"(w1off));           // launder: keep aw loads in-loop
    const char* w1p = (const char*)W1t + w1off;
#pragma unroll
    for (int c = 0; c < 2; ++c) {
        bf16x8 aw[2];
#pragma unroll
        for (int i = 0; i < 2; ++i)
            aw[i] = *(const bf16x8*)(w1p + (size_t)(c * 2 + i) * 1024);

        f32x4 acc1[2][4];
#pragma unroll
        for (int i1 = 0; i1 < 2; ++i1)
#pragma unroll
            for (int im = 0; im < 4; ++im)
                acc1[i1][im] = mfma16(aw[i1], bx[im], (f32x4){0.f, 0.f, 0.f, 0.f});

#pragma unroll
        for (int i1 = 0; i1 < 2; ++i1) {
            int n1b = 64 * w + (c * 2 + i1) * 16 + q * 4;
            const float4 bv = *reinterpret_cast<const float4*>(&b1f[n1b]);
#pragma unroll
            for (int im = 0; im < 4; ++im) {
                int m = im * 16 + L;
                float v0 = fmaxf(acc1[i1][im][0] + bv.x, 0.f);
                float v1 = fmaxf(acc1[i1][im][1] + bv.y, 0.f);
                float v2 = fmaxf(acc1[i1][im][2] + bv.z, 0.f);
                float v3 = fmaxf(acc1[i1][im][3] + bv.w, 0.f);
                uint2 pk;
                pk.x = cvtpk_bf16(v0, v1);
                pk.y = cvtpk_bf16(v2, v3);
                *reinterpret_cast<uint2*>(&h1buf[m * RS + n1b]) = pk;
            }
        }
    }
}

// GEMM2 (K=256, 8 k-chunks): A from registers, B from LDS.
__device__ __forceinline__ void tile_gemm2(
    const bf16x8 (&a2r)[4][8], const ushort* __restrict__ h1buf,
    f32x4 (&acc2)[4][4], int L, int q) {
#pragma unroll
    for (int i2 = 0; i2 < 4; ++i2)
#pragma unroll
        for (int im = 0; im < 4; ++im) acc2[i2][im] = (f32x4){0.f, 0.f, 0.f, 0.f};
#pragma unroll
    for (int kc = 0; kc < 8; ++kc) {
        bf16x8 bh[4];
#pragma unroll
        for (int im = 0; im < 4; ++im) {
            int m = im * 16 + L;
            bh[im] = *(const bf16x8*)(&h1buf[m * RS + kc * 32 + q * 8]);
        }
#pragma unroll
        for (int i2 = 0; i2 < 4; ++i2)
#pragma unroll
            for (int im = 0; im < 4; ++im)
                acc2[i2][im] = mfma16(a2r[i2][kc], bh[im], acc2[i2][im]);
    }
}

// GEMM3: lamb[m] = sum_n2 relu(h2 + b2) * W3 (fp32) -> cross-lane -> lamb slot.
__device__ __forceinline__ void tile_gemm3(
    const f32x4 (&acc2)[4][4], const float* __restrict__ b2f,
    const float* __restrict__ w3f, float (*__restrict__ ls)[64],
    int w, int L, int q) {
    float part[4] = {0.f, 0.f, 0.f, 0.f};
#pragma unroll
    for (int i2 = 0; i2 < 4; ++i2) {
        int n2b = 64 * w + i2 * 16 + q * 4;
        const float4 b2v = *reinterpret_cast<const float4*>(&b2f[n2b]);
        const float4 w3v = *reinterpret_cast<const float4*>(&w3f[n2b]);
#pragma unroll
        for (int im = 0; im < 4; ++im) {
            float h0 = fmaxf(acc2[i2][im][0] + b2v.x, 0.f);
            float h1 = fmaxf(acc2[i2][im][1] + b2v.y, 0.f);
            float h2 = fmaxf(acc2[i2][im][2] + b2v.z, 0.f);
            float h3 = fmaxf(acc2[i2][im][3] + b2v.w, 0.f);
            part[im] = fmaf(h0, w3v.x, part[im]);
            part[im] = fmaf(h1, w3v.y, part[im]);
            part[im] = fmaf(h2, w3v.z, part[im]);
            part[im] = fmaf(h3, w3v.w, part[im]);
        }
    }
#pragma unroll
    for (int im = 0; im < 4; ++im) {
        float pp = part[im];
        pp += __shfl_xor(pp, 16);
        pp += __shfl_xor(pp, 32);
        if (q == 0) ls[w][im * 16 + L] = pp;
    }
}

// ---------------------------------------------------------------------------
// Persistent fused MLP kernel — r7 structure + TILE PAIRING for intra-wave ILP.
// 4 waves, 2 blocks/CU; a2r (W2t slice, 128 regs) register-resident.
// Each iteration processes (ta, tb = ta+GRID): two independent GEMM1+pack
// chains interleave in the front phase; back phase is GEMM2/3(a), then
// sched_barrier(0), then GEMM2/3(b) — acc2-a provably dead before acc2-b
// (prevents 128-reg accumulator overlap -> no spill). 2 barriers per pair
// (= 1/tile, needed for h1s[2] WAR protection), but each segment now holds
// ~2x independent work. Epilogues pipelined one pair behind.
// ---------------------------------------------------------------------------
template <bool XB>
__global__ __launch_bounds__(256, 2) void mlp_kernel(
    const float* __restrict__ x,
    const ushort* __restrict__ xb16,
    const float* __restrict__ b1,
    const float* __restrict__ b2,
    const float* __restrict__ W3,
    const float* __restrict__ b3,
    const ushort* __restrict__ W1t,   // [256][32]  bf16, n1-major
    const ushort* __restrict__ W2t,   // [256][256] bf16, n2-major
    const float4* __restrict__ epi,   // {S, P, Q, 0} per row
    float* __restrict__ out) {
    __shared__ ushort h1s[2][64 * RS];       // 2 x 33792 B (slot per pair-tile)
    __shared__ float b1f[256], b2f[256], w3f[256];
    __shared__ float lamb2[2][2][4][64];     // [parity][pair-slot][wave][row]
    // LDS total: 67584 + 3072 + 4096 = 74752 B  (2 blocks/CU)

    const int tid  = threadIdx.x;
    const int w    = tid >> 6;
    const int lane = tid & 63;
    const int L    = lane & 15;
    const int q    = lane >> 4;

    b1f[tid] = b1[tid];
    b2f[tid] = b2[tid];
    w3f[tid] = W3[tid];
    const float b3v = b3[0];

    // ---- register-resident W2t slice (loaded once, reused every tile) ----
    bf16x8 a2r[4][8];                 // [i2][kc]
#pragma unroll
    for (int i2 = 0; i2 < 4; ++i2)
#pragma unroll
        for (int kc = 0; kc < 8; ++kc)
            a2r[i2][kc] =
                *(const bf16x8*)(W2t + (64 * w + i2 * 16 + L) * 256 + kc * 32 + q * 8);

    // W1t fragment byte-offset (32-bit, SGPR base); laundered per tile_front
    uint32_t w1off = (uint32_t)(((64 * w + L) * 32 + q * 8) * sizeof(ushort));

    // ---- prologue: preload bx for the first pair ----
    int tile = blockIdx.x;
    bf16x8 bxa[4], bxb[4];
    load_bx<XB>(bxa, xb16, x, tile, L, q);
    load_bx<XB>(bxb, xb16, x, tile + GRID_MLP, L, q);   // first pair always exists

    float eSa = 0.f, ePa = 0.f, eQa = 0.f;   // epilogue operands, tile a
    float eSb = 0.f, ePb = 0.f, eQb = 0.f;   // epilogue operands, tile b
    int pta = -1, ptb = -1;                  // pending-epilogue tiles
    int wp = 0;

    __syncthreads();     // b1f/b2f/w3f visible

    for (; tile + GRID_MLP < N_TILES; tile += 2 * GRID_MLP) {
        const int ta = tile, tb = tile + GRID_MLP;

        // ---- front phase: two independent GEMM1+pack chains ----
        tile_front(w1off, W1t, bxa, &h1s[0][0], b1f, w, L, q);
        tile_front(w1off, W1t, bxb, &h1s[1][0], b1f, w, L, q);

        __syncthreads();   // BARRIER 1: h1s[0,1] ready; lamb2[wp^1] visible

        // ---- pipelined epilogues for the previous pair ----
        if (pta >= 0 && tid < 64) {
            {
                float lam = lamb2[wp ^ 1][0][0][tid] + lamb2[wp ^ 1][0][1][tid] +
                            lamb2[wp ^ 1][0][2][tid] + lamb2[wp ^ 1][0][3][tid] + b3v;
                float2 o; o.x = ePa - lam * eSa; o.y = eQa + lam * eSa;
                ((float2*)out)[pta * 64 + tid] = o;
            }
            {
                float lam = lamb2[wp ^ 1][1][0][tid] + lamb2[wp ^ 1][1][1][tid] +
                            lamb2[wp ^ 1][1][2][tid] + lamb2[wp ^ 1][1][3][tid] + b3v;
                float2 o; o.x = ePb - lam * eSb; o.y = eQb + lam * eSb;
                ((float2*)out)[ptb * 64 + tid] = o;
            }
        }

        // ---- back phase, tile a ----
        {
            f32x4 acc2[4][4];
            tile_gemm2(a2r, &h1s[0][0], acc2, L, q);
            tile_gemm3(acc2, b2f, w3f, lamb2[wp][0], w, L, q);
        }
        // bx_a reload for next pair (cover: all of tile b's back phase)
        {
            int tna = tile + 2 * GRID_MLP;
            if (tna >= N_TILES) tna = ta;               // dummy (never consumed)
            load_bx<XB>(bxa, xb16, x, tna, L, q);
        }
        __builtin_amdgcn_sched_barrier(0);  // acc2-a dead before acc2-b born

        // ---- back phase, tile b ----
        {
            f32x4 acc2[4][4];
            tile_gemm2(a2r, &h1s[1][0], acc2, L, q);
            // epi prefetch for (ta,tb), consumed next iteration (cover: GEMM3-b)
            if (tid < 64) {
                float4 ea = epi[(size_t)ta * 64 + tid];
                float4 eb = epi[(size_t)tb * 64 + tid];
                eSa = ea.x; ePa = ea.y; eQa = ea.z;
                eSb = eb.x; ePb = eb.y; eQb = eb.z;
            }
            tile_gemm3(acc2, b2f, w3f, lamb2[wp][1], w, L, q);
        }
        // bx_b reload for next pair
        {
            int tnb = tile + 3 * GRID_MLP;
            if (tnb >= N_TILES) tnb = ta;               // dummy (never consumed)
            load_bx<XB>(bxb, xb16, x, tnb, L, q);
        }

        pta = ta; ptb = tb; wp ^= 1;

        __syncthreads();   // BARRIER 2: protects h1s reuse by next pair's pack
    }

    // ---- leftover single tile (blocks whose tile count is odd) ----
    if (tile < N_TILES) {
        tile_front(w1off, W1t, bxa, &h1s[0][0], b1f, w, L, q);
        __syncthreads();   // h1s[0] ready; lamb2[wp^1] visible
        if (pta >= 0 && tid < 64) {
            {
                float lam = lamb2[wp ^ 1][0][0][tid] + lamb2[wp ^ 1][0][1][tid] +
                            lamb2[wp ^ 1][0][2][tid] + lamb2[wp ^ 1][0][3][tid] + b3v;
                float2 o; o.x = ePa - lam * eSa; o.y = eQa + lam * eSa;
                ((float2*)out)[pta * 64 + tid] = o;
            }
            {
                float lam = lamb2[wp ^ 1][1][0][tid] + lamb2[wp ^ 1][1][1][tid] +
                            lamb2[wp ^ 1][1][2][tid] + lamb2[wp ^ 1][1][3][tid] + b3v;
                float2 o; o.x = ePb - lam * eSb; o.y = eQb + lam * eSb;
                ((float2*)out)[ptb * 64 + tid] = o;
            }
        }
        {
            f32x4 acc2[4][4];
            tile_gemm2(a2r, &h1s[0][0], acc2, L, q);
            if (tid < 64) {
                float4 ea = epi[(size_t)tile * 64 + tid];
                eSa = ea.x; ePa = ea.y; eQa = ea.z;
            }
            tile_gemm3(acc2, b2f, w3f, lamb2[wp][0], w, L, q);
        }
        pta = tile; ptb = -1; wp ^= 1;
    }

    // ---- drain: epilogue for the final pending tile(s) ----
    __syncthreads();
    if (pta >= 0 && tid < 64) {
        {
            float lam = lamb2[wp ^ 1][0][0][tid] + lamb2[wp ^ 1][0][1][tid] +
                        lamb2[wp ^ 1][0][2][tid] + lamb2[wp ^ 1][0][3][tid] + b3v;
            float2 o; o.x = ePa - lam * eSa; o.y = eQa + lam * eSa;
            ((float2*)out)[pta * 64 + tid] = o;
        }
        if (ptb >= 0) {
            float lam = lamb2[wp ^ 1][1][0][tid] + lamb2[wp ^ 1][1][1][tid] +
                        lamb2[wp ^ 1][1][2][tid] + lamb2[wp ^ 1][1][3][tid] + b3v;
            float2 o; o.x = ePb - lam * eSb; o.y = eQb + lam * eSb;
            ((float2*)out)[ptb * 64 + tid] = o;
        }
    }
}

// ---------------------------------------------------------------------------
extern "C" void kernel_launch(void* const* d_in, const int* in_sizes, int n_in,
                              void* d_out, int out_size, void* d_ws, size_t ws_size,
                              hipStream_t stream) {
    const float* x  = (const float*)d_in[0];
    const float* T  = (const float*)d_in[1];
    const float* W1 = (const float*)d_in[2];
    const float* b1 = (const float*)d_in[3];
    const float* W2 = (const float*)d_in[4];
    const float* b2 = (const float*)d_in[5];
    const float* W3 = (const float*)d_in[6];
    const float* b3 = (const float*)d_in[7];

    // ws layout: [xb16 (opt, 26.2 MB)] epi (6.55 MB) W1t (16KB) W2t (128KB)
    const size_t xb_bytes = (size_t)M_ROWS * 32 * 2;
    const size_t epi_b    = (size_t)M_ROWS * 16;
    const size_t small    = epi_b + 8192 * 2 + 65536 * 2;
    const int    do_xb    = (ws_size >= xb_bytes + small) ? 1 : 0;

    char* ws = (char*)d_ws;
    ushort* xb16 = (ushort*)ws;
    char* base = ws + (do_xb ? xb_bytes : 0);
    float4* epi  = (float4*)(base);
    ushort* W1t  = (ushort*)(base + epi_b);
    ushort* W2t  = (ushort*)(base + epi_b + 8192 * 2);

    hipLaunchKernelGGL(prep_kernel, dim3(B_CNT + 256 + 32), dim3(256), 0, stream,
                       x, T, W1, W2, xb16, epi, W1t, W2t, do_xb);
    if (do_xb) {
        hipLaunchKernelGGL((mlp_kernel<true>), dim3(GRID_MLP), dim3(256), 0, stream,
                           x, xb16, b1, b2, W3, b3, W1t, W2t, epi, (float*)d_out);
    } else {
        hipLaunchKernelGGL((mlp_kernel<false>), dim3(GRID_MLP), dim3(256), 0, stream,
                           x, xb16, b1, b2, W3, b3, W1t, W2t, epi, (float*)d_out);
    }
}

// Round 11
// 177.125 us; speedup vs baseline: 1.0592x; 1.0408x over previous
//
#include <hip/hip_runtime.h>
#include <stdint.h>

// Problem constants: B=2048, C=200, F=32, H=256. All tensors fp32 in/out.
// M = B*C = 409600 rows of 32 features, contiguous in x.
#define M_ROWS 409600
#define B_CNT  2048
#define C_CNT  200
#define N_TILES (M_ROWS / 64)    // 6400 tiles of 64 rows
#define GRID_MLP 512             // persistent blocks: 2 per CU

typedef __attribute__((ext_vector_type(8))) short bf16x8;   // 8 bf16 = 4 VGPRs
typedef __attribute__((ext_vector_type(4))) float f32x4;

// NOTE (measured r7/r9/r10): SQ_LDS_BANK_CONFLICT ~4.92M/dispatch is the
// inherent serialization of wave64 ds_read_b128 (1KB/wave over 128B/clk LDS)
// — invariant across RS-pad and XOR-swizzle. Not a fixable conflict.
// NOTE (measured r3/r5/r6/r10): ANY added live state on the r7 loop spills
// (the loop sits at the 256-reg/wave boundary). This round removes 3-4 regs
// of cross-barrier liveness (epilogue prefetch) — nothing else changes.

// round-to-nearest-even f32 -> bf16 bits (scalar path, prep kernel)
__device__ __forceinline__ ushort f2bf(float f) {
    uint32_t u = __float_as_uint(f);
    u += 0x7fffu + ((u >> 16) & 1u);
    return (ushort)(u >> 16);
}

// packed RNE f32x2 -> bf16x2 (single HW instruction)
__device__ __forceinline__ uint32_t cvtpk_bf16(float lo, float hi) {
    uint32_t r;
    asm("v_cvt_pk_bf16_f32 %0, %1, %2" : "=v"(r) : "v"(lo), "v"(hi));
    return r;
}

__device__ __forceinline__ f32x4 mfma16(bf16x8 a, bf16x8 b, f32x4 c) {
    return __builtin_amdgcn_mfma_f32_16x16x32_bf16(a, b, c, 0, 0, 0);
}

__device__ __forceinline__ bf16x8 pack8(float4 a, float4 b) {
    bf16x8 r;
    r[0] = (short)f2bf(a.x); r[1] = (short)f2bf(a.y);
    r[2] = (short)f2bf(a.z); r[3] = (short)f2bf(a.w);
    r[4] = (short)f2bf(b.x); r[5] = (short)f2bf(b.y);
    r[6] = (short)f2bf(b.z); r[7] = (short)f2bf(b.w);
    return r;
}

// ---------------------------------------------------------------------------
// Prep kernel (unchanged, measured-good):
//   blocks [0,2048):   one coalesced pass over the x row: bf16 copy (xb16),
//                      sinflow/iinflow, fused epilogue operand
//                      epi[gm] = {S, P, Q, 0}:
//                        P = S + sinflow - outflow*S,  Q = I + iinflow - outflow*I
//   blocks [2048,2304): W2^T -> bf16
//   blocks [2304,2336): W1^T -> bf16
// ---------------------------------------------------------------------------
__global__ __launch_bounds__(256) void prep_kernel(
    const float* __restrict__ x, const float* __restrict__ T,
    const float* __restrict__ W1, const float* __restrict__ W2,
    ushort* __restrict__ xb16, float4* __restrict__ epi,
    ushort* __restrict__ W1t, ushort* __restrict__ W2t, int do_xb) {
    int blk = blockIdx.x, t = threadIdx.x;
    if (blk < B_CNT) {
        __shared__ float Sr[C_CNT], Ir[C_CNT];
        const float4* xr = (const float4*)(x + (size_t)blk * 6400);  // 1600 f4
        ushort4* xw = (ushort4*)(xb16 + (size_t)blk * 6400);
#pragma unroll
        for (int i = 0; i < 7; ++i) {
            int i4 = i * 256 + t;
            if (i4 < 1600) {
                float4 v = xr[i4];
                if (do_xb) {
                    ushort4 u;
                    u.x = f2bf(v.x); u.y = f2bf(v.y);
                    u.z = f2bf(v.z); u.w = f2bf(v.w);
                    xw[i4] = u;
                }
                if ((i4 & 7) == 0) {           // element i4*4 is feature 0 of c
                    int c = i4 >> 3;
                    Sr[c] = v.x; Ir[c] = v.y;
                }
            }
        }
        __syncthreads();
        if (t < C_CNT) {
            float as = 0.f, ai = 0.f;
            for (int cp = 0; cp < C_CNT; ++cp) {
                float tv = T[cp * C_CNT + t];        // coalesced over t, L2-hot
                as = fmaf(Sr[cp], tv, as);
                ai = fmaf(Ir[cp], tv, ai);
            }
            float S = Sr[t], I = Ir[t];
            float of = 1.0f - T[t * C_CNT + t];
            float4 e;
            e.x = S;
            e.y = S + as - of * S;   // P
            e.z = I + ai - of * I;   // Q
            e.w = 0.f;
            epi[(size_t)blk * C_CNT + t] = e;
        }
    } else if (blk < B_CNT + 256) {
        int n = blk - B_CNT;                          // one n2 row per block
        W2t[n * 256 + t] = f2bf(W2[t * 256 + n]);     // write coalesced
    } else {
        int idx = (blk - B_CNT - 256) * 256 + t;      // 0..8191
        int n = idx >> 5, k = idx & 31;
        W1t[idx] = f2bf(W1[k * 256 + n]);
    }
}

// ---------------------------------------------------------------------------
// Persistent fused MLP kernel — r7 structure (4 waves, 2 blocks/CU, one
// barrier/tile, GEMM1 2-chunk split, bx reload after the GEMM2 peak) with
// ONE change: the epilogue's epi operands are no longer prefetched across
// the barrier (3-4 regs in the tightest front region). Instead the epi
// float4 load is ISSUED right after the barrier and CONSUMED after GEMM2
// (~800 cyc cover); its registers live only in the GEMM2 region (slack).
// Per iteration t:
//   [chunk c=0,1: aw(2) load | 8 MFMA GEMM1 | pack 32 cols -> h1s[buf]]
//   BARRIER | issue epi(t-1) load | GEMM2(t) regs x LDS
//   | epilogue(t-1): lamb2 + epi -> out | bx reload(t+1) | GEMM3(t)
// ---------------------------------------------------------------------------
template <bool XB>
__global__ __launch_bounds__(256, 2) void mlp_kernel(
    const float* __restrict__ x,
    const ushort* __restrict__ xb16,
    const float* __restrict__ b1,
    const float* __restrict__ b2,
    const float* __restrict__ W3,
    const float* __restrict__ b3,
    const ushort* __restrict__ W1t,   // [256][32]  bf16, n1-major
    const ushort* __restrict__ W2t,   // [256][256] bf16, n2-major
    const float4* __restrict__ epi,   // {S, P, Q, 0} per row
    float* __restrict__ out) {
    constexpr int RS = 264;  // h1 row stride (ushorts): rows 16B-aligned
    __shared__ ushort h1s[2][64 * RS];       // 2 x 33792 B
    __shared__ float b1f[256], b2f[256], w3f[256];
    __shared__ float lamb2[2][4][64];        // parity double buffer

    const int tid  = threadIdx.x;
    const int w    = tid >> 6;
    const int lane = tid & 63;
    const int L    = lane & 15;
    const int q    = lane >> 4;

    b1f[tid] = b1[tid];
    b2f[tid] = b2[tid];
    w3f[tid] = W3[tid];
    const float b3v = b3[0];

    // ---- register-resident W2t slice (loaded once, reused every tile) ----
    bf16x8 a2r[4][8];                 // [i2][kc]
#pragma unroll
    for (int i2 = 0; i2 < 4; ++i2)
#pragma unroll
        for (int kc = 0; kc < 8; ++kc)
            a2r[i2][kc] =
                *(const bf16x8*)(W2t + (64 * w + i2 * 16 + L) * 256 + kc * 32 + q * 8);

    // W1t fragment byte-offset (32-bit, SGPR base); laundered per iteration
    uint32_t w1off = (uint32_t)(((64 * w + L) * 32 + q * 8) * sizeof(ushort));

    // ---- prologue: preload bx for the first tile ----
    int tile = blockIdx.x;
    bf16x8 bx[4];
#pragma unroll
    for (int i = 0; i < 4; ++i) {
        if (XB) {
            bx[i] = *(const bf16x8*)(xb16 + (size_t)(tile * 64 + i * 16 + L) * 32 + q * 8);
        } else {
            const float4* xr =
                (const float4*)(x + (size_t)(tile * 64 + i * 16 + L) * 32 + q * 8);
            bx[i] = pack8(xr[0], xr[1]);
        }
    }

    int ptile = -1;      // tile whose epilogue is pending
    int buf = 0, wp = 0;

    __syncthreads();     // b1f/b2f/w3f visible

    for (; tile < N_TILES; tile += GRID_MLP) {
        // ---- GEMM1+pack in TWO chunks (acc1 live range = 32 regs) ----
        asm volatile("" : "+v"(w1off));
        const char* w1p = (const char*)W1t + w1off;
#pragma unroll
        for (int c = 0; c < 2; ++c) {
            bf16x8 aw[2];
#pragma unroll
            for (int i = 0; i < 2; ++i)
                aw[i] = *(const bf16x8*)(w1p + (size_t)(c * 2 + i) * 1024);

            f32x4 acc1[2][4];
#pragma unroll
            for (int i1 = 0; i1 < 2; ++i1)
#pragma unroll
                for (int im = 0; im < 4; ++im)
                    acc1[i1][im] = mfma16(aw[i1], bx[im], (f32x4){0.f, 0.f, 0.f, 0.f});

            // pack these 32 n1-columns (bias+relu fp32, cvt_pk bf16) -> h1s[buf]
            // Safe pre-barrier: buf == buf(t-2); all waves passed barrier(t-1),
            // whose program order puts GEMM2(t-2) (last reader of buf) first.
#pragma unroll
            for (int i1 = 0; i1 < 2; ++i1) {
                int n1b = 64 * w + (c * 2 + i1) * 16 + q * 4;
                const float4 bv = *reinterpret_cast<const float4*>(&b1f[n1b]);
#pragma unroll
                for (int im = 0; im < 4; ++im) {
                    int m = im * 16 + L;
                    float v0 = fmaxf(acc1[i1][im][0] + bv.x, 0.f);
                    float v1 = fmaxf(acc1[i1][im][1] + bv.y, 0.f);
                    float v2 = fmaxf(acc1[i1][im][2] + bv.z, 0.f);
                    float v3 = fmaxf(acc1[i1][im][3] + bv.w, 0.f);
                    uint2 pk;
                    pk.x = cvtpk_bf16(v0, v1);
                    pk.y = cvtpk_bf16(v2, v3);
                    *reinterpret_cast<uint2*>(&h1s[buf][m * RS + n1b]) = pk;
                }
            }
        }

        __syncthreads();   // THE barrier: h1s[buf] ready; lamb2[wp^1] visible

        // ---- issue the epilogue operand load NOW; consume after GEMM2 ----
        // (compiler leaves the waitcnt at the use point -> GEMM2 covers L3)
        float4 ev = {0.f, 0.f, 0.f, 0.f};
        if (ptile >= 0 && tid < 64)
            ev = epi[(size_t)ptile * 64 + tid];

        // ---- GEMM2 (K=256, 8 k-chunks): A from registers, B from LDS ----
        f32x4 acc2[4][4];
#pragma unroll
        for (int i2 = 0; i2 < 4; ++i2)
#pragma unroll
            for (int im = 0; im < 4; ++im) acc2[i2][im] = (f32x4){0.f, 0.f, 0.f, 0.f};

#pragma unroll
        for (int kc = 0; kc < 8; ++kc) {
            bf16x8 bh[4];
#pragma unroll
            for (int im = 0; im < 4; ++im) {
                int m = im * 16 + L;
                bh[im] = *(const bf16x8*)(&h1s[buf][m * RS + kc * 32 + q * 8]);
            }
#pragma unroll
            for (int i2 = 0; i2 < 4; ++i2)
#pragma unroll
                for (int im = 0; im < 4; ++im)
                    acc2[i2][im] = mfma16(a2r[i2][kc], bh[im], acc2[i2][im]);
        }

        // ---- pipelined epilogue for tile t-1 (operands just arrived) ----
        if (ptile >= 0 && tid < 64) {
            float lam = lamb2[wp ^ 1][0][tid] + lamb2[wp ^ 1][1][tid] +
                        lamb2[wp ^ 1][2][tid] + lamb2[wp ^ 1][3][tid] + b3v;
            float2 o;
            o.x = ev.y - lam * ev.x;   // P - lam*S
            o.y = ev.z + lam * ev.x;   // Q + lam*S
            ((float2*)out)[ptile * 64 + tid] = o;   // coalesced 8B store
        }

        // ---- bx reload for next tile: AFTER the GEMM2 register peak ----
        {
            int tn = tile + GRID_MLP;
            if (tn >= N_TILES) tn = tile;   // harmless dummy reload on last iter
            const size_t mn0 = (size_t)tn * 64;
#pragma unroll
            for (int i = 0; i < 4; ++i) {
                if (XB) {
                    bx[i] = *(const bf16x8*)(xb16 + (mn0 + i * 16 + L) * 32 + q * 8);
                } else {
                    const float4* xr =
                        (const float4*)(x + (mn0 + i * 16 + L) * 32 + q * 8);
                    bx[i] = pack8(xr[0], xr[1]);
                }
            }
        }

        // ---- GEMM3: lamb[m] = sum_n2 relu(h2 + b2) * W3 (fp32, exact) ----
        float part[4] = {0.f, 0.f, 0.f, 0.f};
#pragma unroll
        for (int i2 = 0; i2 < 4; ++i2) {
            int n2b = 64 * w + i2 * 16 + q * 4;
            const float4 b2v = *reinterpret_cast<const float4*>(&b2f[n2b]);
            const float4 w3v = *reinterpret_cast<const float4*>(&w3f[n2b]);
#pragma unroll
            for (int im = 0; im < 4; ++im) {
                float h0 = fmaxf(acc2[i2][im][0] + b2v.x, 0.f);
                float h1 = fmaxf(acc2[i2][im][1] + b2v.y, 0.f);
                float h2 = fmaxf(acc2[i2][im][2] + b2v.z, 0.f);
                float h3 = fmaxf(acc2[i2][im][3] + b2v.w, 0.f);
                part[im] = fmaf(h0, w3v.x, part[im]);
                part[im] = fmaf(h1, w3v.y, part[im]);
                part[im] = fmaf(h2, w3v.z, part[im]);
                part[im] = fmaf(h3, w3v.w, part[im]);
            }
        }

#pragma unroll
        for (int im = 0; im < 4; ++im) {
            float pp = part[im];
            pp += __shfl_xor(pp, 16);
            pp += __shfl_xor(pp, 32);
            if (q == 0) lamb2[wp][w][im * 16 + L] = pp;
        }
        // lamb2[wp] is consumed only after the NEXT barrier.

        ptile = tile;
        buf ^= 1;
        wp ^= 1;
    }

    // ---- drain: epilogue for the final tile (epi read directly) ----
    __syncthreads();
    if (ptile >= 0 && tid < 64) {
        float4 ev = epi[(size_t)ptile * 64 + tid];
        float lam = lamb2[wp ^ 1][0][tid] + lamb2[wp ^ 1][1][tid] +
                    lamb2[wp ^ 1][2][tid] + lamb2[wp ^ 1][3][tid] + b3v;
        float2 o;
        o.x = ev.y - lam * ev.x;
        o.y = ev.z + lam * ev.x;
        ((float2*)out)[ptile * 64 + tid] = o;
    }
}

// ---------------------------------------------------------------------------
extern "C" void kernel_launch(void* const* d_in, const int* in_sizes, int n_in,
                              void* d_out, int out_size, void* d_ws, size_t ws_size,
                              hipStream_t stream) {
    const float* x  = (const float*)d_in[0];
    const float* T  = (const float*)d_in[1];
    const float* W1 = (const float*)d_in[2];
    const float* b1 = (const float*)d_in[3];
    const float* W2 = (const float*)d_in[4];
    const float* b2 = (const float*)d_in[5];
    const float* W3 = (const float*)d_in[6];
    const float* b3 = (const float*)d_in[7];

    // ws layout: [xb16 (opt, 26.2 MB)] epi (6.55 MB) W1t (16KB) W2t (128KB)
    const size_t xb_bytes = (size_t)M_ROWS * 32 * 2;
    const size_t epi_b    = (size_t)M_ROWS * 16;
    const size_t small    = epi_b + 8192 * 2 + 65536 * 2;
    const int    do_xb    = (ws_size >= xb_bytes + small) ? 1 : 0;

    char* ws = (char*)d_ws;
    ushort* xb16 = (ushort*)ws;
    char* base = ws + (do_xb ? xb_bytes : 0);
    float4* epi  = (float4*)(base);
    ushort* W1t  = (ushort*)(base + epi_b);
    ushort* W2t  = (ushort*)(base + epi_b + 8192 * 2);

    hipLaunchKernelGGL(prep_kernel, dim3(B_CNT + 256 + 32), dim3(256), 0, stream,
                       x, T, W1, W2, xb16, epi, W1t, W2t, do_xb);
    if (do_xb) {
        hipLaunchKernelGGL((mlp_kernel<true>), dim3(GRID_MLP), dim3(256), 0, stream,
                           x, xb16, b1, b2, W3, b3, W1t, W2t, epi, (float*)d_out);
    } else {
        hipLaunchKernelGGL((mlp_kernel<false>), dim3(GRID_MLP), dim3(256), 0, stream,
                           x, xb16, b1, b2, W3, b3, W1t, W2t, epi, (float*)d_out);
    }
}